// Round 1
// baseline (363.389 us; speedup 1.0000x reference)
//
#include <hip/hip_runtime.h>

// DistributedMemory forward:
//   inputs[b,:] = P[doc_ids[b],:] + sum_c W[context_ids[b,c],:]      [B,128]
//   out[b,s]    = dot(inputs[b,:], outputs[:, sample_ids[b,s]])      [B,S]
//
// Shapes: B=16384, C=8, S=10, D=128, N_WORDS=100000, N_DOCS=1e6
// All f32; ids int32.

#define VEC_DIM 128
#define N_WORDS_C 100000
#define CTX 8
#define NSAMP 10

__global__ __launch_bounds__(128) void dm_fwd_kernel(
    const int* __restrict__ doc_ids,
    const int* __restrict__ context_ids,
    const int* __restrict__ sample_ids,
    const float* __restrict__ P,      // [N_DOCS, 128]
    const float* __restrict__ W,      // [N_WORDS, 128]
    const float* __restrict__ outs,   // [128, N_WORDS]
    float* __restrict__ out)          // [B, S]
{
    const int b = blockIdx.x;
    const int d = threadIdx.x;        // 0..127, owns one vector dim
    const int lane = d & 63;
    const int wave = d >> 6;

    // --- build inputs[b][d] : coalesced row reads (128 consecutive floats) ---
    float v = P[(long)doc_ids[b] * VEC_DIM + d];
    #pragma unroll
    for (int c = 0; c < CTX; ++c) {
        v += W[(long)context_ids[b * CTX + c] * VEC_DIM + d];
    }

    // --- S dot products against columns of `outs` (strided gather) ---
    __shared__ float partial[2 * NSAMP];
    #pragma unroll
    for (int s = 0; s < NSAMP; ++s) {
        const int w = sample_ids[b * NSAMP + s];       // broadcast load
        float p = v * outs[(long)d * N_WORDS_C + w];   // stride-400KB gather
        // 64-lane wave reduce
        #pragma unroll
        for (int off = 32; off > 0; off >>= 1)
            p += __shfl_down(p, off, 64);
        if (lane == 0) partial[wave * NSAMP + s] = p;
    }
    __syncthreads();

    if (d < NSAMP) {
        out[b * NSAMP + d] = partial[d] + partial[NSAMP + d];
    }
}

extern "C" void kernel_launch(void* const* d_in, const int* in_sizes, int n_in,
                              void* d_out, int out_size, void* d_ws, size_t ws_size,
                              hipStream_t stream) {
    const int*   doc_ids     = (const int*)d_in[0];
    const int*   context_ids = (const int*)d_in[1];
    const int*   sample_ids  = (const int*)d_in[2];
    const float* P           = (const float*)d_in[3];
    const float* W           = (const float*)d_in[4];
    const float* outs        = (const float*)d_in[5];
    float*       out         = (float*)d_out;

    const int B = in_sizes[0];  // 16384

    dm_fwd_kernel<<<B, 128, 0, stream>>>(doc_ids, context_ids, sample_ids,
                                         P, W, outs, out);
}

// Round 2
// 43.287 us; speedup vs baseline: 8.3948x; 8.3948x over previous
//
#include <hip/hip_runtime.h>

// DistributedMemory forward:
//   inputs[b,:] = P[doc_ids[b],:] + sum_c W[context_ids[b,c],:]      [B,128]
//   out[b,s]    = dot(inputs[b,:], outputs[:, sample_ids[b,s]])      [B,S]
//
// Shapes: B=16384, C=8, S=10, D=128, N_WORDS=100000, N_DOCS=1e6. All f32.
//
// R1 -> R2: outs[d*N_WORDS+w] column gather fetched a full cache line per
// 4B element (FETCH_SIZE 1.28 GB vs ~110 MB footprint). Fix: transpose outs
// into d_ws once per call (streaming, ~102 MB), then gather contiguous
// 512 B rows. Main kernel vectorized to float4, 32 lanes per batch element.

#define VEC_DIM 128
#define N_WORDS_C 100000
#define CTX 8
#define NSAMP 10

// ---------------- transpose: outs[128, N_WORDS] -> outsT[N_WORDS, 128] ----
// Tile 32x32 via LDS. N_WORDS = 100000 = 3125*32 exactly; 128 = 4*32.
__global__ __launch_bounds__(256) void transpose_kernel(
    const float* __restrict__ in,   // [128, N_WORDS]
    float* __restrict__ outT)       // [N_WORDS, 128]
{
    __shared__ float tile[32][33];
    const int tx = threadIdx.x;         // 0..31
    const int ty = threadIdx.y;         // 0..7
    const int col0 = blockIdx.x * 32;   // word index base
    const int row0 = blockIdx.y * 32;   // dim index base

    #pragma unroll
    for (int i = 0; i < 32; i += 8) {
        // read coalesced along words
        tile[ty + i][tx] = in[(long)(row0 + ty + i) * N_WORDS_C + col0 + tx];
    }
    __syncthreads();
    #pragma unroll
    for (int i = 0; i < 32; i += 8) {
        // write coalesced along dims
        outT[(long)(col0 + ty + i) * VEC_DIM + row0 + tx] = tile[tx][ty + i];
    }
}

// ---------------- main: 32 lanes per batch element, float4 per lane -------
__global__ __launch_bounds__(256) void dm_fwd_kernel(
    const int* __restrict__ doc_ids,
    const int* __restrict__ context_ids,
    const int* __restrict__ sample_ids,
    const float* __restrict__ P,       // [N_DOCS, 128]
    const float* __restrict__ W,       // [N_WORDS, 128]
    const float* __restrict__ outsT,   // [N_WORDS, 128]  (transposed)
    float* __restrict__ out)           // [B, S]
{
    const int t = threadIdx.x & 31;                      // lane in sub-group
    const int b = blockIdx.x * 8 + (threadIdx.x >> 5);   // batch element

    const float4* __restrict__ P4  = (const float4*)P;
    const float4* __restrict__ W4  = (const float4*)W;
    const float4* __restrict__ O4  = (const float4*)outsT;

    // inputs[b] : float4 per lane, 32 lanes cover 128 dims
    float4 v = P4[(long)doc_ids[b] * 32 + t];
    #pragma unroll
    for (int c = 0; c < CTX; ++c) {
        float4 w4 = W4[(long)context_ids[b * CTX + c] * 32 + t];
        v.x += w4.x; v.y += w4.y; v.z += w4.z; v.w += w4.w;
    }

    // preload sample ids (uniform within sub-group -> broadcast)
    int wids[NSAMP];
    #pragma unroll
    for (int s = 0; s < NSAMP; ++s) wids[s] = sample_ids[b * NSAMP + s];

    #pragma unroll
    for (int s = 0; s < NSAMP; ++s) {
        float4 o = O4[(long)wids[s] * 32 + t];           // 512 B contiguous
        float p = v.x * o.x + v.y * o.y + v.z * o.z + v.w * o.w;
        // reduce within 32-lane sub-group
        #pragma unroll
        for (int off = 16; off > 0; off >>= 1)
            p += __shfl_down(p, off, 32);
        if (t == 0) out[b * NSAMP + s] = p;
    }
}

// ---------------- fallback (no workspace): direct strided gather ----------
__global__ __launch_bounds__(128) void dm_fwd_direct(
    const int* __restrict__ doc_ids,
    const int* __restrict__ context_ids,
    const int* __restrict__ sample_ids,
    const float* __restrict__ P,
    const float* __restrict__ W,
    const float* __restrict__ outs,    // [128, N_WORDS]
    float* __restrict__ out)
{
    const int b = blockIdx.x;
    const int d = threadIdx.x;
    const int lane = d & 63;
    const int wave = d >> 6;

    float v = P[(long)doc_ids[b] * VEC_DIM + d];
    #pragma unroll
    for (int c = 0; c < CTX; ++c)
        v += W[(long)context_ids[b * CTX + c] * VEC_DIM + d];

    __shared__ float partial[2 * NSAMP];
    #pragma unroll
    for (int s = 0; s < NSAMP; ++s) {
        const int w = sample_ids[b * NSAMP + s];
        float p = v * outs[(long)d * N_WORDS_C + w];
        #pragma unroll
        for (int off = 32; off > 0; off >>= 1)
            p += __shfl_down(p, off, 64);
        if (lane == 0) partial[wave * NSAMP + s] = p;
    }
    __syncthreads();
    if (d < NSAMP) out[b * NSAMP + d] = partial[d] + partial[NSAMP + d];
}

extern "C" void kernel_launch(void* const* d_in, const int* in_sizes, int n_in,
                              void* d_out, int out_size, void* d_ws, size_t ws_size,
                              hipStream_t stream) {
    const int*   doc_ids     = (const int*)d_in[0];
    const int*   context_ids = (const int*)d_in[1];
    const int*   sample_ids  = (const int*)d_in[2];
    const float* P           = (const float*)d_in[3];
    const float* W           = (const float*)d_in[4];
    const float* outs        = (const float*)d_in[5];
    float*       out         = (float*)d_out;

    const int B = in_sizes[0];  // 16384
    const size_t needed = (size_t)N_WORDS_C * VEC_DIM * sizeof(float);  // 51.2 MB

    if (ws_size >= needed) {
        float* outsT = (float*)d_ws;
        dim3 tg(N_WORDS_C / 32, VEC_DIM / 32);   // 3125 x 4
        transpose_kernel<<<tg, dim3(32, 8), 0, stream>>>(outs, outsT);
        dm_fwd_kernel<<<B / 8, 256, 0, stream>>>(doc_ids, context_ids, sample_ids,
                                                 P, W, outsT, out);
    } else {
        dm_fwd_direct<<<B, 128, 0, stream>>>(doc_ids, context_ids, sample_ids,
                                             P, W, outs, out);
    }
}